// Round 12
// baseline (636.942 us; speedup 1.0000x reference)
//
#include <hip/hip_runtime.h>

#define N_TOK 131072
#define D_IN  512
#define GHID  64
#define E_EXP 16
#define CAPE  8192
#define H_DIM 128
#define O_DIM 512

typedef __attribute__((ext_vector_type(8))) short bf16x8;
typedef __attribute__((ext_vector_type(4))) float f32x4;

__device__ __forceinline__ ushort f2bf(float f) {
    uint u = __builtin_bit_cast(uint, f);
    u = u + 0x7FFFu + ((u >> 16) & 1u);   // RNE
    return (ushort)(u >> 16);
}
__device__ __forceinline__ float bf2f(ushort s) {
    return __builtin_bit_cast(float, ((uint)s) << 16);
}

// ---------------- Wsplit: Wg1 [512][64] f32 -> WgT[3][64][512] bf16 planes ----------------
__global__ __launch_bounds__(64) void wsplit_kernel(const float* __restrict__ Wg1,
                                                    ushort* __restrict__ WgT)
{
    int n = blockIdx.x;                  // 0..63
    for (int k = threadIdx.x; k < 512; k += 64) {
        float v = Wg1[(size_t)k * GHID + n];
        ushort s0 = f2bf(v); float r1 = v - bf2f(s0);
        ushort s1 = f2bf(r1); float r2 = r1 - bf2f(s1);
        ushort s2 = f2bf(r2);
        WgT[(size_t)(0 * 64 + n) * 512 + k] = s0;
        WgT[(size_t)(1 * 64 + n) * 512 + k] = s1;
        WgT[(size_t)(2 * 64 + n) * 512 + k] = s2;
    }
}

// One K-chunk (32 K-elems) of the gating layer-1: split + 6-term MFMA.
// Arithmetic identical to R7-R11 (same split chains, same MFMA accumulation order).
__device__ __forceinline__ void gate_step(
    const float4& x0, const float4& x1, const float4& x2, const float4& x3,
    int kc, const ushort* __restrict__ wg_base,
    f32x4 (&acc)[2][4])
{
    union U { bf16x8 v; ushort u[8]; };
    U p0[2], p1[2], p2[2];
    float f0[8] = {x0.x, x0.y, x0.z, x0.w, x1.x, x1.y, x1.z, x1.w};
    float f1[8] = {x2.x, x2.y, x2.z, x2.w, x3.x, x3.y, x3.z, x3.w};
    #pragma unroll
    for (int q = 0; q < 8; ++q) {
        float v = f0[q];
        ushort s0 = f2bf(v); float r1 = v - bf2f(s0);
        ushort s1 = f2bf(r1); float r2 = r1 - bf2f(s1);
        p0[0].u[q] = s0; p1[0].u[q] = s1; p2[0].u[q] = f2bf(r2);
    }
    #pragma unroll
    for (int q = 0; q < 8; ++q) {
        float v = f1[q];
        ushort s0 = f2bf(v); float r1 = v - bf2f(s0);
        ushort s1 = f2bf(r1); float r2 = r1 - bf2f(s1);
        p0[1].u[q] = s0; p1[1].u[q] = s1; p2[1].u[q] = f2bf(r2);
    }
    #pragma unroll
    for (int fj = 0; fj < 4; ++fj) {
        const ushort* bp = wg_base + (size_t)fj * 16 * 512 + kc * 32;
        bf16x8 b0 = *reinterpret_cast<const bf16x8*>(bp);
        bf16x8 b1 = *reinterpret_cast<const bf16x8*>(bp + 64 * 512);
        bf16x8 b2 = *reinterpret_cast<const bf16x8*>(bp + 2 * 64 * 512);
        #pragma unroll
        for (int fi = 0; fi < 2; ++fi) {
            acc[fi][fj] = __builtin_amdgcn_mfma_f32_16x16x32_bf16(p0[fi].v, b0, acc[fi][fj], 0, 0, 0);
            acc[fi][fj] = __builtin_amdgcn_mfma_f32_16x16x32_bf16(p0[fi].v, b1, acc[fi][fj], 0, 0, 0);
            acc[fi][fj] = __builtin_amdgcn_mfma_f32_16x16x32_bf16(p1[fi].v, b0, acc[fi][fj], 0, 0, 0);
            acc[fi][fj] = __builtin_amdgcn_mfma_f32_16x16x32_bf16(p0[fi].v, b2, acc[fi][fj], 0, 0, 0);
            acc[fi][fj] = __builtin_amdgcn_mfma_f32_16x16x32_bf16(p1[fi].v, b1, acc[fi][fj], 0, 0, 0);
            acc[fi][fj] = __builtin_amdgcn_mfma_f32_16x16x32_bf16(p2[fi].v, b0, acc[fi][fj], 0, 0, 0);
        }
    }
}

// ---------------- K1: gating. 16.9 KB LDS, 8 blocks/CU (100% wave occupancy). ----------------
// 256 thr = 4 waves; wave = 32 tokens x 64 hidden -> block covers 128 tokens.
// Layer-2: PROVEN sequential scalar order, done in TWO half-passes over hs[128][33]
// (lacc persists in registers across the barrier -> bit-identical argmax).
__global__ __launch_bounds__(256, 8) void gating_mfma_kernel(
    const float* __restrict__ x, const ushort* __restrict__ WgT,
    const float* __restrict__ bg1, const float* __restrict__ Wg2,
    const float* __restrict__ bg2, int* __restrict__ top_expert)
{
    __shared__ float hs[128][33];        // 16.9 KB -> 8 blocks/CU

    const int tid  = threadIdx.x;
    const int lane = tid & 63, w = tid >> 6;
    const int l15  = lane & 15, l4 = lane >> 4;
    const int tile = blockIdx.x * 128 + w * 32;         // wave's 32-token tile

    const float4* xr0 = reinterpret_cast<const float4*>(x) + (size_t)(tile + l15) * 128 + l4 * 2;
    const float4* xr1 = xr0 + (size_t)16 * 128;

    const ushort* wg_base = WgT + (size_t)l15 * 512 + l4 * 8;   // + fj*16*512, plane*64*512, kc*32

    f32x4 acc[2][4] = {};   // [fi][fj]

    float4 c0 = xr0[0], c1 = xr0[1], c2 = xr1[0], c3 = xr1[1];
    #pragma unroll 2
    for (int kc = 0; kc < 16; ++kc) {
        float4 n0 = c0, n1 = c1, n2 = c2, n3 = c3;
        if (kc < 15) {
            n0 = xr0[(kc + 1) * 8];     n1 = xr0[(kc + 1) * 8 + 1];
            n2 = xr1[(kc + 1) * 8];     n3 = xr1[(kc + 1) * 8 + 1];
        }
        __builtin_amdgcn_sched_barrier(0);
        gate_step(c0, c1, c2, c3, kc, wg_base, acc);
        __builtin_amdgcn_sched_barrier(0);
        c0 = n0; c1 = n1; c2 = n2; c3 = n3;
    }

    // ---- bias + relu in regs ----
    float bg1v[4];
    #pragma unroll
    for (int fj = 0; fj < 4; ++fj) bg1v[fj] = bg1[fj * 16 + l15];
    #pragma unroll
    for (int fi = 0; fi < 2; ++fi)
        #pragma unroll
        for (int fj = 0; fj < 4; ++fj)
            #pragma unroll
            for (int j = 0; j < 4; ++j) {
                float v = acc[fi][fj][j] + bg1v[fj];
                acc[fi][fj][j] = v > 0.f ? v : 0.f;
            }

    float lacc[16];
    #pragma unroll
    for (int e = 0; e < 16; ++e) lacc[e] = bg2[e];

    // ---- layer 2 in two half-passes (k 0..31 then 32..63), PROVEN order preserved ----
    #pragma unroll
    for (int half = 0; half < 2; ++half) {
        if (half == 1) __syncthreads();   // pass-A reads complete before overwrite
        #pragma unroll
        for (int fj = 0; fj < 2; ++fj) {
            int fjj = half * 2 + fj;
            #pragma unroll
            for (int fi = 0; fi < 2; ++fi)
                #pragma unroll
                for (int j = 0; j < 4; ++j) {
                    int row = w * 32 + fi * 16 + l4 * 4 + j;
                    hs[row][fj * 16 + l15] = acc[fi][fjj][j];
                }
        }
        __syncthreads();
        if (tid < 128) {
            #pragma unroll 8
            for (int k = 0; k < 32; ++k) {
                float hv = hs[tid][k];
                int kk = half * 32 + k;
                #pragma unroll
                for (int e = 0; e < 16; ++e) lacc[e] += hv * Wg2[kk * 16 + e];
            }
        }
    }

    if (tid < 128) {
        float best = lacc[0]; int be = 0;
        #pragma unroll
        for (int e = 1; e < 16; ++e) {
            if (lacc[e] > best) { best = lacc[e]; be = e; }
        }
        top_expert[blockIdx.x * 128 + tid] = be;
    }
}

// ---------------- P1..P3: routing ----------------
__global__ __launch_bounds__(256) void count_kernel(const int* __restrict__ te,
                                                    int* __restrict__ blockCounts)
{
    __shared__ int cnt[16];
    if (threadIdx.x < 16) cnt[threadIdx.x] = 0;
    __syncthreads();
    int base = blockIdx.x * 512;
    for (int i = threadIdx.x; i < 512; i += 256)
        atomicAdd(&cnt[te[base + i]], 1);
    __syncthreads();
    if (threadIdx.x < 16) blockCounts[blockIdx.x * 16 + threadIdx.x] = cnt[threadIdx.x];
}

__global__ void scan_kernel(const int* __restrict__ blockCounts,
                            int* __restrict__ blockOffs, int* __restrict__ totals,
                            int* __restrict__ dropCount)
{
    int e = threadIdx.x;
    if (e == 0) *dropCount = 0;
    if (e < 16) {
        int run = 0;
        for (int b = 0; b < 256; ++b) {
            blockOffs[b * 16 + e] = run;
            run += blockCounts[b * 16 + e];
        }
        totals[e] = run;
    }
}

__global__ __launch_bounds__(64) void scatter_kernel(const int* __restrict__ te,
        const int* __restrict__ blockOffs, int* __restrict__ slot_token,
        int* __restrict__ dropCount, int* __restrict__ dropList)
{
    const int b = blockIdx.x;
    const int lane = threadIdx.x;
    int running[16];
    #pragma unroll
    for (int e = 0; e < 16; ++e) running[e] = blockOffs[b * 16 + e];
    const unsigned long long lt = (lane == 0) ? 0ull : ((~0ull) >> (64 - lane));
    const int base = b * 512;
    for (int g = 0; g < 8; ++g) {
        int n = base + g * 64 + lane;
        int e = te[n];
        int p = 0;
        #pragma unroll
        for (int ee = 0; ee < 16; ++ee) {
            unsigned long long bal = __ballot(e == ee);
            if (e == ee) p = running[ee] + __popcll(bal & lt);
            running[ee] += __popcll(bal);
        }
        if (p < CAPE) {
            slot_token[e * CAPE + p] = n;
        } else {
            int di = atomicAdd(dropCount, 1);
            dropList[di] = n;
        }
    }
}

// ---------------- Wc: transpose + fp32->bf16:  in [E][R][C] f32 -> out [E][C][R] bf16 ----------------
template<int R, int C>
__global__ __launch_bounds__(256) void cvt_transpose_kernel(const float* __restrict__ in,
                                                            ushort* __restrict__ out)
{
    __shared__ float s[32][33];
    const int tilesC = C / 32;
    const int tilesR = R / 32;
    int bid = blockIdx.x;
    int e = bid / (tilesR * tilesC);
    int t = bid % (tilesR * tilesC);
    int r0 = (t / tilesC) * 32, c0 = (t % tilesC) * 32;
    const float* ip = in + (size_t)e * R * C;
    ushort* op = out + (size_t)e * C * R;
    int j = threadIdx.x & 31, i0 = threadIdx.x >> 5;
    #pragma unroll
    for (int p = 0; p < 4; ++p) {
        int i = i0 + p * 8;
        s[i][j] = ip[(size_t)(r0 + i) * C + (c0 + j)];
    }
    __syncthreads();
    #pragma unroll
    for (int p = 0; p < 4; ++p) {
        int cc = i0 + p * 8;
        op[(size_t)(c0 + cc) * R + (r0 + j)] = f2bf(s[j][cc]);
    }
}

// ---------------- K4: per-expert MLP + softmax via bf16 MFMA (unchanged from R11) ----------------
__global__ __launch_bounds__(512, 4) void expert_mfma_kernel(
    const float* __restrict__ x,
    const ushort* __restrict__ W1T, const float* __restrict__ b1,
    const ushort* __restrict__ W2T, const float* __restrict__ b2,
    const int* __restrict__ slot_token, const int* __restrict__ totals,
    float* __restrict__ out)
{
    __shared__ ushort xs_u[64 * 512];   // 64 KB; reused: h after phase 1, f32 transpose in epilogue
    __shared__ int    toks[64];
    __shared__ float  redm[8][64];
    __shared__ float  reds[8][64];

    const int tid  = threadIdx.x;
    const int e    = blockIdx.x >> 7;
    const int sb   = blockIdx.x & 127;
    const int slot0 = sb * 64;
    int vc = totals[e]; if (vc > CAPE) vc = CAPE;
    if (slot0 >= vc) return;
    int nt = vc - slot0; if (nt > 64) nt = 64;

    const int lane = tid & 63;
    const int wid  = tid >> 6;
    const int l15  = lane & 15;
    const int l4   = lane >> 4;

    if (tid < 64) toks[tid] = (tid < nt) ? slot_token[e * CAPE + slot0 + tid] : -1;
    __syncthreads();

    char* xsb = (char*)xs_u;

    // ---- stage: issue all 8 gather loads (pinned), then convert+write to swizzled LDS ----
    {
        float4 ga[8], gb[8];
        #pragma unroll
        for (int it = 0; it < 8; ++it) {
            int g = it * 512 + tid;
            int row = g >> 6, cg = g & 63;
            int tk = toks[row];
            float4 z = make_float4(0.f, 0.f, 0.f, 0.f);
            if (tk >= 0) {
                const float4* xp = reinterpret_cast<const float4*>(&x[(size_t)tk * D_IN + cg * 8]);
                ga[it] = xp[0]; gb[it] = xp[1];
            } else { ga[it] = z; gb[it] = z; }
        }
        __builtin_amdgcn_sched_barrier(0);
        #pragma unroll
        for (int it = 0; it < 8; ++it) {
            int g = it * 512 + tid;
            int row = g >> 6, cg = g & 63;
            float f[8] = {ga[it].x, ga[it].y, ga[it].z, ga[it].w,
                          gb[it].x, gb[it].y, gb[it].z, gb[it].w};
            union { bf16x8 v; ushort u[8]; } wv;
            #pragma unroll
            for (int q = 0; q < 8; ++q) wv.u[q] = f2bf(f[q]);
            *reinterpret_cast<bf16x8*>(xsb + row * 1024 + ((cg * 16) ^ ((row & 7) << 4))) = wv.v;
        }
    }
    __syncthreads();

    f32x4 acc1[4] = {};
    {
        const ushort* w1p = W1T + ((size_t)e * H_DIM + wid * 16 + l15) * D_IN + l4 * 8;
        bf16x8 bcur = *reinterpret_cast<const bf16x8*>(w1p);
        #pragma unroll 4
        for (int kt = 0; kt < 512; kt += 32) {
            bf16x8 bnxt = bcur;
            if (kt + 32 < 512) bnxt = *reinterpret_cast<const bf16x8*>(w1p + kt + 32);
            __builtin_amdgcn_sched_barrier(0);
            #pragma unroll
            for (int fi = 0; fi < 4; ++fi) {
                int r = fi * 16 + l15;
                bf16x8 a = *reinterpret_cast<const bf16x8*>(xsb + r * 1024 + ((kt * 2 + l4 * 16) ^ ((r & 7) << 4)));
                acc1[fi] = __builtin_amdgcn_mfma_f32_16x16x32_bf16(a, bcur, acc1[fi], 0, 0, 0);
            }
            bcur = bnxt;
        }
    }
    __syncthreads();

    {
        int col = wid * 16 + l15;
        float bv = b1[e * H_DIM + col];
        #pragma unroll
        for (int fi = 0; fi < 4; ++fi) {
            #pragma unroll
            for (int j = 0; j < 4; ++j) {
                int row = fi * 16 + l4 * 4 + j;
                float v = acc1[fi][j] + bv;
                v = v > 0.f ? v : 0.f;
                *reinterpret_cast<ushort*>(xsb + row * 256 + ((col * 2) ^ ((row & 7) << 4))) = f2bf(v);
            }
        }
    }
    __syncthreads();

    f32x4 acc2[4][4] = {};
    {
        const ushort* w2p = W2T + ((size_t)e * O_DIM + wid * 64 + l15) * H_DIM + l4 * 8;
        #pragma unroll
        for (int kt = 0; kt < 128; kt += 32) {
            bf16x8 a[4];
            #pragma unroll
            for (int fi = 0; fi < 4; ++fi) {
                int r = fi * 16 + l15;
                a[fi] = *reinterpret_cast<const bf16x8*>(xsb + r * 256 + ((kt * 2 + l4 * 16) ^ ((r & 7) << 4)));
            }
            #pragma unroll
            for (int fj = 0; fj < 4; ++fj) {
                bf16x8 bfrag = *reinterpret_cast<const bf16x8*>(w2p + (size_t)fj * 16 * H_DIM + kt);
                #pragma unroll
                for (int fi = 0; fi < 4; ++fi)
                    acc2[fi][fj] = __builtin_amdgcn_mfma_f32_16x16x32_bf16(a[fi], bfrag, acc2[fi][fj], 0, 0, 0);
            }
        }
    }
    #pragma unroll
    for (int fj = 0; fj < 4; ++fj) {
        float bv = b2[e * O_DIM + wid * 64 + fj * 16 + l15];
        #pragma unroll
        for (int fi = 0; fi < 4; ++fi)
            #pragma unroll
            for (int j = 0; j < 4; ++j) acc2[fi][fj][j] += bv;
    }

    #pragma unroll
    for (int fi = 0; fi < 4; ++fi)
        #pragma unroll
        for (int j = 0; j < 4; ++j) {
            float m = acc2[fi][0][j];
            #pragma unroll
            for (int fj = 1; fj < 4; ++fj) m = fmaxf(m, acc2[fi][fj][j]);
            #pragma unroll
            for (int msk = 1; msk < 16; msk <<= 1) m = fmaxf(m, __shfl_xor(m, msk, 64));
            if (l15 == 0) redm[wid][fi * 16 + l4 * 4 + j] = m;
        }
    __syncthreads();
    #pragma unroll
    for (int fi = 0; fi < 4; ++fi)
        #pragma unroll
        for (int j = 0; j < 4; ++j) {
            int r = fi * 16 + l4 * 4 + j;
            float M = redm[0][r];
            #pragma unroll
            for (int w = 1; w < 8; ++w) M = fmaxf(M, redm[w][r]);
            float s = 0.f;
            #pragma unroll
            for (int fj = 0; fj < 4; ++fj) {
                float ex = expf(acc2[fi][fj][j] - M);
                acc2[fi][fj][j] = ex;
                s += ex;
            }
            #pragma unroll
            for (int msk = 1; msk < 16; msk <<= 1) s += __shfl_xor(s, msk, 64);
            if (l15 == 0) reds[wid][r] = s;
        }
    __syncthreads();

    #pragma unroll
    for (int fi = 0; fi < 4; ++fi)
        #pragma unroll
        for (int j = 0; j < 4; ++j) {
            int r = fi * 16 + l4 * 4 + j;
            float S = reds[0][r];
            #pragma unroll
            for (int w = 1; w < 8; ++w) S += reds[w][r];
            float inv = 1.f / S;
            #pragma unroll
            for (int fj = 0; fj < 4; ++fj) acc2[fi][fj][j] *= inv;
        }

    float* tf = reinterpret_cast<float*>(xs_u);    // [16][516] pad
    #pragma unroll
    for (int p = 0; p < 4; ++p) {
        __syncthreads();
        #pragma unroll
        for (int fj = 0; fj < 4; ++fj)
            #pragma unroll
            for (int j = 0; j < 4; ++j)
                tf[(l4 * 4 + j) * 516 + wid * 64 + fj * 16 + l15] = acc2[p][fj][j];
        __syncthreads();
        #pragma unroll
        for (int it = 0; it < 4; ++it) {
            int idx = it * 512 + tid;
            int r16 = idx >> 7, c4 = idx & 127;
            int tk = toks[p * 16 + r16];
            if (tk >= 0) {
                float4 v = *reinterpret_cast<const float4*>(&tf[r16 * 516 + c4 * 4]);
                *reinterpret_cast<float4*>(&out[(size_t)tk * O_DIM + c4 * 4]) = v;
            }
        }
    }
}

// ---------------- K5: zero rows of dropped tokens ----------------
__global__ __launch_bounds__(256) void zero_dropped_kernel(const int* __restrict__ dropCount,
        const int* __restrict__ dropList, float* __restrict__ out)
{
    int cnt = *dropCount;
    for (int i = blockIdx.x; i < cnt; i += gridDim.x) {
        int n = dropList[i];
        reinterpret_cast<float2*>(&out[(size_t)n * O_DIM])[threadIdx.x] = make_float2(0.f, 0.f);
    }
}

extern "C" void kernel_launch(void* const* d_in, const int* in_sizes, int n_in,
                              void* d_out, int out_size, void* d_ws, size_t ws_size,
                              hipStream_t stream) {
    (void)in_sizes; (void)n_in; (void)out_size; (void)ws_size;
    const float* x   = (const float*)d_in[0];
    const float* Wg1 = (const float*)d_in[1];
    const float* bg1 = (const float*)d_in[2];
    const float* Wg2 = (const float*)d_in[3];
    const float* bg2 = (const float*)d_in[4];
    const float* W1  = (const float*)d_in[5];
    const float* b1  = (const float*)d_in[6];
    const float* W2  = (const float*)d_in[7];
    const float* b2  = (const float*)d_in[8];
    float* out = (float*)d_out;

    char* ws = (char*)d_ws;
    size_t off = 0;
    int* dropCount   = (int*)(ws + off); off += 256;
    int* top_expert  = (int*)(ws + off); off += (size_t)N_TOK * 4;
    int* blockCounts = (int*)(ws + off); off += 256 * 16 * 4;
    int* blockOffs   = (int*)(ws + off); off += 256 * 16 * 4;
    int* totals      = (int*)(ws + off); off += 256;
    int* slot_token  = (int*)(ws + off); off += (size_t)E_EXP * CAPE * 4;
    int* dropList    = (int*)(ws + off); off += (size_t)N_TOK * 4;
    ushort* W1T      = (ushort*)(ws + off); off += (size_t)E_EXP * D_IN * H_DIM * 2;
    ushort* W2T      = (ushort*)(ws + off); off += (size_t)E_EXP * H_DIM * O_DIM * 2;
    ushort* WgT      = (ushort*)(ws + off); off += (size_t)3 * GHID * D_IN * 2;

    wsplit_kernel<<<GHID, 64, 0, stream>>>(Wg1, WgT);
    cvt_transpose_kernel<D_IN, H_DIM><<<E_EXP * (D_IN/32) * (H_DIM/32), 256, 0, stream>>>(W1, W1T);
    cvt_transpose_kernel<H_DIM, O_DIM><<<E_EXP * (H_DIM/32) * (O_DIM/32), 256, 0, stream>>>(W2, W2T);
    gating_mfma_kernel<<<N_TOK / 128, 256, 0, stream>>>(x, WgT, bg1, Wg2, bg2, top_expert);
    count_kernel<<<N_TOK / 512, 256, 0, stream>>>(top_expert, blockCounts);
    scan_kernel<<<1, 64, 0, stream>>>(blockCounts, blockOffs, totals, dropCount);
    scatter_kernel<<<N_TOK / 512, 64, 0, stream>>>(top_expert, blockOffs, slot_token, dropCount, dropList);
    expert_mfma_kernel<<<E_EXP * (CAPE / 64), 512, 0, stream>>>(x, W1T, b1, W2T, b2, slot_token, totals, out);
    zero_dropped_kernel<<<256, 256, 0, stream>>>(dropCount, dropList, out);
}

// Round 13
// 326.653 us; speedup vs baseline: 1.9499x; 1.9499x over previous
//
#include <hip/hip_runtime.h>

#define N_TOK 131072
#define D_IN  512
#define GHID  64
#define E_EXP 16
#define CAPE  8192
#define H_DIM 128
#define O_DIM 512

typedef __attribute__((ext_vector_type(8))) short bf16x8;
typedef __attribute__((ext_vector_type(4))) short bf16x4;
typedef __attribute__((ext_vector_type(4))) float f32x4;

__device__ __forceinline__ ushort f2bf(float f) {
    uint u = __builtin_bit_cast(uint, f);
    u = u + 0x7FFFu + ((u >> 16) & 1u);   // RNE
    return (ushort)(u >> 16);
}
__device__ __forceinline__ float bf2f(ushort s) {
    return __builtin_bit_cast(float, ((uint)s) << 16);
}

// ---------------- wpack_gate: Wg1 [512][64] f32 -> WgF[kc16][fj4][plane3][lane64][8] bf16 ----------------
// Fragment-contiguous: a wave's B-load is base + lane*16B (single coalesced segment).
__global__ __launch_bounds__(64) void wpack_gate(const float* __restrict__ Wg1,
                                                 ushort* __restrict__ WgF)
{
    int kc = blockIdx.x >> 2, fj = blockIdx.x & 3;
    int lane = threadIdx.x;
    int col = fj * 16 + (lane & 15);
    int k0 = kc * 32 + (lane >> 4) * 8;
    union { bf16x8 v; ushort u[8]; } p0, p1, p2;
    #pragma unroll
    for (int q = 0; q < 8; ++q) {
        float v = Wg1[(size_t)(k0 + q) * GHID + col];
        ushort s0 = f2bf(v); float r1 = v - bf2f(s0);
        ushort s1 = f2bf(r1); float r2 = r1 - bf2f(s1);
        p0.u[q] = s0; p1.u[q] = s1; p2.u[q] = f2bf(r2);
    }
    ushort* dst = WgF + (size_t)((kc * 4 + fj) * 3) * 512 + lane * 8;
    *reinterpret_cast<bf16x8*>(dst)        = p0.v;
    *reinterpret_cast<bf16x8*>(dst + 512)  = p1.v;
    *reinterpret_cast<bf16x8*>(dst + 1024) = p2.v;
}

// ---------------- wpack1: W1 [E][512][128] f32 -> W1F[e][wid8][kt16][lane64][8] bf16 ----------------
__global__ __launch_bounds__(64) void wpack1_kernel(const float* __restrict__ W1,
                                                    ushort* __restrict__ W1F)
{
    int b = blockIdx.x;                       // 2048 = e*128 + wid*16 + kt
    int e = b >> 7, wid = (b >> 4) & 7, kt = b & 15;
    int lane = threadIdx.x;
    int h  = wid * 16 + (lane & 15);
    int k0 = kt * 32 + (lane >> 4) * 8;
    union { bf16x8 v; ushort u[8]; } p;
    #pragma unroll
    for (int q = 0; q < 8; ++q)
        p.u[q] = f2bf(W1[((size_t)e * D_IN + k0 + q) * H_DIM + h]);
    *reinterpret_cast<bf16x8*>(W1F + ((size_t)(e * 8 + wid) * 16 + kt) * 512 + lane * 8) = p.v;
}

// ---------------- wpack2: W2 [E][128][512] f32 -> W2F[e][wid8][fj4][kt4][lane64][8] bf16 ----------------
__global__ __launch_bounds__(64) void wpack2_kernel(const float* __restrict__ W2,
                                                    ushort* __restrict__ W2F)
{
    int b = blockIdx.x;                       // 2048 = e*128 + wid*16 + fj*4 + kt
    int e = b >> 7, wid = (b >> 4) & 7, fj = (b >> 2) & 3, kt = b & 3;
    int lane = threadIdx.x;
    int o  = wid * 64 + fj * 16 + (lane & 15);
    int k0 = kt * 32 + (lane >> 4) * 8;
    union { bf16x8 v; ushort u[8]; } p;
    #pragma unroll
    for (int q = 0; q < 8; ++q)
        p.u[q] = f2bf(W2[((size_t)e * H_DIM + k0 + q) * O_DIM + o]);
    *reinterpret_cast<bf16x8*>(W2F + (((size_t)(e * 8 + wid) * 4 + fj) * 4 + kt) * 512 + lane * 8) = p.v;
}

// One K-chunk of gating layer-1: split + 6-term MFMA. Arithmetic identical to R7-R12
// (same split chains, same MFMA accumulation order); only B addressing is fragment-contiguous.
__device__ __forceinline__ void gate_step(
    const float4& x0, const float4& x1, const float4& x2, const float4& x3,
    int kc, const ushort* __restrict__ wg_lane,     // = WgF + lane*8
    f32x4 (&acc)[2][4])
{
    union U { bf16x8 v; ushort u[8]; };
    U p0[2], p1[2], p2[2];
    float f0[8] = {x0.x, x0.y, x0.z, x0.w, x1.x, x1.y, x1.z, x1.w};
    float f1[8] = {x2.x, x2.y, x2.z, x2.w, x3.x, x3.y, x3.z, x3.w};
    #pragma unroll
    for (int q = 0; q < 8; ++q) {
        float v = f0[q];
        ushort s0 = f2bf(v); float r1 = v - bf2f(s0);
        ushort s1 = f2bf(r1); float r2 = r1 - bf2f(s1);
        p0[0].u[q] = s0; p1[0].u[q] = s1; p2[0].u[q] = f2bf(r2);
    }
    #pragma unroll
    for (int q = 0; q < 8; ++q) {
        float v = f1[q];
        ushort s0 = f2bf(v); float r1 = v - bf2f(s0);
        ushort s1 = f2bf(r1); float r2 = r1 - bf2f(s1);
        p0[1].u[q] = s0; p1[1].u[q] = s1; p2[1].u[q] = f2bf(r2);
    }
    #pragma unroll
    for (int fj = 0; fj < 4; ++fj) {
        const ushort* bp = wg_lane + (size_t)((kc * 4 + fj) * 3) * 512;
        bf16x8 b0 = *reinterpret_cast<const bf16x8*>(bp);
        bf16x8 b1 = *reinterpret_cast<const bf16x8*>(bp + 512);
        bf16x8 b2 = *reinterpret_cast<const bf16x8*>(bp + 1024);
        #pragma unroll
        for (int fi = 0; fi < 2; ++fi) {
            acc[fi][fj] = __builtin_amdgcn_mfma_f32_16x16x32_bf16(p0[fi].v, b0, acc[fi][fj], 0, 0, 0);
            acc[fi][fj] = __builtin_amdgcn_mfma_f32_16x16x32_bf16(p0[fi].v, b1, acc[fi][fj], 0, 0, 0);
            acc[fi][fj] = __builtin_amdgcn_mfma_f32_16x16x32_bf16(p1[fi].v, b0, acc[fi][fj], 0, 0, 0);
            acc[fi][fj] = __builtin_amdgcn_mfma_f32_16x16x32_bf16(p0[fi].v, b2, acc[fi][fj], 0, 0, 0);
            acc[fi][fj] = __builtin_amdgcn_mfma_f32_16x16x32_bf16(p1[fi].v, b1, acc[fi][fj], 0, 0, 0);
            acc[fi][fj] = __builtin_amdgcn_mfma_f32_16x16x32_bf16(p2[fi].v, b0, acc[fi][fj], 0, 0, 0);
        }
    }
}

// ---------------- K1: gating (R11 structure; fragment-contiguous B). ----------------
__global__ __launch_bounds__(256, 4) void gating_mfma_kernel(
    const float* __restrict__ x, const ushort* __restrict__ WgF,
    const float* __restrict__ bg1, const float* __restrict__ Wg2,
    const float* __restrict__ bg2, int* __restrict__ top_expert)
{
    __shared__ float hs[128][65];        // 33.3 KB, +1 pad

    const int tid  = threadIdx.x;
    const int lane = tid & 63, w = tid >> 6;
    const int l15  = lane & 15, l4 = lane >> 4;
    const int tile = blockIdx.x * 128 + w * 32;

    const float4* xr0 = reinterpret_cast<const float4*>(x) + (size_t)(tile + l15) * 128 + l4 * 2;
    const float4* xr1 = xr0 + (size_t)16 * 128;

    const ushort* wg_lane = WgF + lane * 8;

    f32x4 acc[2][4] = {};   // [fi][fj]

    float4 c0 = xr0[0], c1 = xr0[1], c2 = xr1[0], c3 = xr1[1];
    #pragma unroll 2
    for (int kc = 0; kc < 16; ++kc) {
        float4 n0 = c0, n1 = c1, n2 = c2, n3 = c3;
        if (kc < 15) {
            n0 = xr0[(kc + 1) * 8];     n1 = xr0[(kc + 1) * 8 + 1];
            n2 = xr1[(kc + 1) * 8];     n3 = xr1[(kc + 1) * 8 + 1];
        }
        __builtin_amdgcn_sched_barrier(0);
        gate_step(c0, c1, c2, c3, kc, wg_lane, acc);
        __builtin_amdgcn_sched_barrier(0);
        c0 = n0; c1 = n1; c2 = n2; c3 = n3;
    }

    // ---- epilogue: bias + relu -> hs (fp32, padded) ----
    float bg1v[4];
    #pragma unroll
    for (int fj = 0; fj < 4; ++fj) bg1v[fj] = bg1[fj * 16 + l15];

    #pragma unroll
    for (int fi = 0; fi < 2; ++fi)
        #pragma unroll
        for (int fj = 0; fj < 4; ++fj) {
            #pragma unroll
            for (int j = 0; j < 4; ++j) {
                int row = w * 32 + fi * 16 + l4 * 4 + j;
                float v = acc[fi][fj][j] + bg1v[fj];
                hs[row][fj * 16 + l15] = v > 0.f ? v : 0.f;
            }
        }
    __syncthreads();

    // ---- layer 2 + argmax: PROVEN sequential scalar order; tid < 128 only ----
    if (tid < 128) {
        float lacc[16];
        #pragma unroll
        for (int e = 0; e < 16; ++e) lacc[e] = bg2[e];
        #pragma unroll 8
        for (int k = 0; k < 64; ++k) {
            float hv = hs[tid][k];
            #pragma unroll
            for (int e = 0; e < 16; ++e) lacc[e] += hv * Wg2[k * 16 + e];
        }
        float best = lacc[0]; int be = 0;
        #pragma unroll
        for (int e = 1; e < 16; ++e) {
            if (lacc[e] > best) { best = lacc[e]; be = e; }
        }
        top_expert[blockIdx.x * 128 + tid] = be;
    }
}

// ---------------- P1..P3: routing ----------------
__global__ __launch_bounds__(256) void count_kernel(const int* __restrict__ te,
                                                    int* __restrict__ blockCounts)
{
    __shared__ int cnt[16];
    if (threadIdx.x < 16) cnt[threadIdx.x] = 0;
    __syncthreads();
    int base = blockIdx.x * 512;
    for (int i = threadIdx.x; i < 512; i += 256)
        atomicAdd(&cnt[te[base + i]], 1);
    __syncthreads();
    if (threadIdx.x < 16) blockCounts[blockIdx.x * 16 + threadIdx.x] = cnt[threadIdx.x];
}

__global__ void scan_kernel(const int* __restrict__ blockCounts,
                            int* __restrict__ blockOffs, int* __restrict__ totals,
                            int* __restrict__ dropCount)
{
    int e = threadIdx.x;
    if (e == 0) *dropCount = 0;
    if (e < 16) {
        int run = 0;
        for (int b = 0; b < 256; ++b) {
            blockOffs[b * 16 + e] = run;
            run += blockCounts[b * 16 + e];
        }
        totals[e] = run;
    }
}

__global__ __launch_bounds__(64) void scatter_kernel(const int* __restrict__ te,
        const int* __restrict__ blockOffs, int* __restrict__ slot_token,
        int* __restrict__ dropCount, int* __restrict__ dropList)
{
    const int b = blockIdx.x;
    const int lane = threadIdx.x;
    int running[16];
    #pragma unroll
    for (int e = 0; e < 16; ++e) running[e] = blockOffs[b * 16 + e];
    const unsigned long long lt = (lane == 0) ? 0ull : ((~0ull) >> (64 - lane));
    const int base = b * 512;
    for (int g = 0; g < 8; ++g) {
        int n = base + g * 64 + lane;
        int e = te[n];
        int p = 0;
        #pragma unroll
        for (int ee = 0; ee < 16; ++ee) {
            unsigned long long bal = __ballot(e == ee);
            if (e == ee) p = running[ee] + __popcll(bal & lt);
            running[ee] += __popcll(bal);
        }
        if (p < CAPE) {
            slot_token[e * CAPE + p] = n;
        } else {
            int di = atomicAdd(dropCount, 1);
            dropList[di] = n;
        }
    }
}

// ---------------- K4: per-expert MLP + softmax via bf16 MFMA (fragment-contiguous weights) ----------------
__global__ __launch_bounds__(512, 4) void expert_mfma_kernel(
    const float* __restrict__ x,
    const ushort* __restrict__ W1F, const float* __restrict__ b1,
    const ushort* __restrict__ W2F, const float* __restrict__ b2,
    const int* __restrict__ slot_token, const int* __restrict__ totals,
    float* __restrict__ out)
{
    __shared__ ushort xs_u[64 * 512];   // 64 KB; reused: h after phase 1, f32 transpose in epilogue
    __shared__ int    toks[64];
    __shared__ float  redm[8][64];
    __shared__ float  reds[8][64];

    const int tid  = threadIdx.x;
    const int e    = blockIdx.x >> 7;
    const int sb   = blockIdx.x & 127;
    const int slot0 = sb * 64;
    int vc = totals[e]; if (vc > CAPE) vc = CAPE;
    if (slot0 >= vc) return;
    int nt = vc - slot0; if (nt > 64) nt = 64;

    const int lane = tid & 63;
    const int wid  = tid >> 6;
    const int l15  = lane & 15;
    const int l4   = lane >> 4;

    if (tid < 64) toks[tid] = (tid < nt) ? slot_token[e * CAPE + slot0 + tid] : -1;
    __syncthreads();

    char* xsb = (char*)xs_u;

    // ---- stage: two half-row contiguous 16B/lane loads; LDS bytes identical to previous rounds ----
    {
        float4 ga[8], gb[8];
        #pragma unroll
        for (int it = 0; it < 8; ++it) {
            int g = it * 512 + tid;
            int row = g >> 6, c = g & 63;
            int tk = toks[row];
            float4 z = make_float4(0.f, 0.f, 0.f, 0.f);
            if (tk >= 0) {
                const float* xrow = &x[(size_t)tk * D_IN];
                ga[it] = *reinterpret_cast<const float4*>(xrow + c * 4);          // floats [c*4, +4)
                gb[it] = *reinterpret_cast<const float4*>(xrow + 256 + c * 4);    // floats [256+c*4, +4)
            } else { ga[it] = z; gb[it] = z; }
        }
        __builtin_amdgcn_sched_barrier(0);
        #pragma unroll
        for (int it = 0; it < 8; ++it) {
            int g = it * 512 + tid;
            int row = g >> 6, c = g & 63;
            int swz = (row & 7) << 4;
            union { bf16x4 v; ushort u[4]; } wa, wb;
            wa.u[0] = f2bf(ga[it].x); wa.u[1] = f2bf(ga[it].y);
            wa.u[2] = f2bf(ga[it].z); wa.u[3] = f2bf(ga[it].w);
            wb.u[0] = f2bf(gb[it].x); wb.u[1] = f2bf(gb[it].y);
            wb.u[2] = f2bf(gb[it].z); wb.u[3] = f2bf(gb[it].w);
            *reinterpret_cast<bf16x4*>(xsb + row * 1024 + ((c * 8) ^ swz))       = wa.v;
            *reinterpret_cast<bf16x4*>(xsb + row * 1024 + ((512 + c * 8) ^ swz)) = wb.v;
        }
    }
    __syncthreads();

    f32x4 acc1[4] = {};
    {
        const ushort* w1l = W1F + (size_t)(e * 8 + wid) * 16 * 512 + lane * 8;
        bf16x8 bcur = *reinterpret_cast<const bf16x8*>(w1l);
        #pragma unroll 4
        for (int kt = 0; kt < 16; ++kt) {
            bf16x8 bnxt = bcur;
            if (kt + 1 < 16) bnxt = *reinterpret_cast<const bf16x8*>(w1l + (kt + 1) * 512);
            __builtin_amdgcn_sched_barrier(0);
            #pragma unroll
            for (int fi = 0; fi < 4; ++fi) {
                int r = fi * 16 + l15;
                bf16x8 a = *reinterpret_cast<const bf16x8*>(xsb + r * 1024 + ((kt * 64 + l4 * 16) ^ ((r & 7) << 4)));
                acc1[fi] = __builtin_amdgcn_mfma_f32_16x16x32_bf16(a, bcur, acc1[fi], 0, 0, 0);
            }
            bcur = bnxt;
        }
    }
    __syncthreads();

    {
        int col = wid * 16 + l15;
        float bv = b1[e * H_DIM + col];
        #pragma unroll
        for (int fi = 0; fi < 4; ++fi) {
            #pragma unroll
            for (int j = 0; j < 4; ++j) {
                int row = fi * 16 + l4 * 4 + j;
                float v = acc1[fi][j] + bv;
                v = v > 0.f ? v : 0.f;
                *reinterpret_cast<ushort*>(xsb + row * 256 + ((col * 2) ^ ((row & 7) << 4))) = f2bf(v);
            }
        }
    }
    __syncthreads();

    f32x4 acc2[4][4] = {};
    {
        const ushort* w2l = W2F + (size_t)(e * 8 + wid) * 16 * 512 + lane * 8;
        #pragma unroll
        for (int kt = 0; kt < 4; ++kt) {
            bf16x8 a[4];
            #pragma unroll
            for (int fi = 0; fi < 4; ++fi) {
                int r = fi * 16 + l15;
                a[fi] = *reinterpret_cast<const bf16x8*>(xsb + r * 256 + ((kt * 64 + l4 * 16) ^ ((r & 7) << 4)));
            }
            #pragma unroll
            for (int fj = 0; fj < 4; ++fj) {
                bf16x8 bfrag = *reinterpret_cast<const bf16x8*>(w2l + (size_t)(fj * 4 + kt) * 512);
                #pragma unroll
                for (int fi = 0; fi < 4; ++fi)
                    acc2[fi][fj] = __builtin_amdgcn_mfma_f32_16x16x32_bf16(a[fi], bfrag, acc2[fi][fj], 0, 0, 0);
            }
        }
    }
    #pragma unroll
    for (int fj = 0; fj < 4; ++fj) {
        float bv = b2[e * O_DIM + wid * 64 + fj * 16 + l15];
        #pragma unroll
        for (int fi = 0; fi < 4; ++fi)
            #pragma unroll
            for (int j = 0; j < 4; ++j) acc2[fi][fj][j] += bv;
    }

    #pragma unroll
    for (int fi = 0; fi < 4; ++fi)
        #pragma unroll
        for (int j = 0; j < 4; ++j) {
            float m = acc2[fi][0][j];
            #pragma unroll
            for (int fj = 1; fj < 4; ++fj) m = fmaxf(m, acc2[fi][fj][j]);
            #pragma unroll
            for (int msk = 1; msk < 16; msk <<= 1) m = fmaxf(m, __shfl_xor(m, msk, 64));
            if (l15 == 0) redm[wid][fi * 16 + l4 * 4 + j] = m;
        }
    __syncthreads();
    #pragma unroll
    for (int fi = 0; fi < 4; ++fi)
        #pragma unroll
        for (int j = 0; j < 4; ++j) {
            int r = fi * 16 + l4 * 4 + j;
            float M = redm[0][r];
            #pragma unroll
            for (int w = 1; w < 8; ++w) M = fmaxf(M, redm[w][r]);
            float s = 0.f;
            #pragma unroll
            for (int fj = 0; fj < 4; ++fj) {
                float ex = expf(acc2[fi][fj][j] - M);
                acc2[fi][fj][j] = ex;
                s += ex;
            }
            #pragma unroll
            for (int msk = 1; msk < 16; msk <<= 1) s += __shfl_xor(s, msk, 64);
            if (l15 == 0) reds[wid][r] = s;
        }
    __syncthreads();

    #pragma unroll
    for (int fi = 0; fi < 4; ++fi)
        #pragma unroll
        for (int j = 0; j < 4; ++j) {
            int r = fi * 16 + l4 * 4 + j;
            float S = reds[0][r];
            #pragma unroll
            for (int w = 1; w < 8; ++w) S += reds[w][r];
            float inv = 1.f / S;
            #pragma unroll
            for (int fj = 0; fj < 4; ++fj) acc2[fi][fj][j] *= inv;
        }

    float* tf = reinterpret_cast<float*>(xs_u);    // [16][516] pad
    #pragma unroll
    for (int p = 0; p < 4; ++p) {
        __syncthreads();
        #pragma unroll
        for (int fj = 0; fj < 4; ++fj)
            #pragma unroll
            for (int j = 0; j < 4; ++j)
                tf[(l4 * 4 + j) * 516 + wid * 64 + fj * 16 + l15] = acc2[p][fj][j];
        __syncthreads();
        #pragma unroll
        for (int it = 0; it < 4; ++it) {
            int idx = it * 512 + tid;
            int r16 = idx >> 7, c4 = idx & 127;
            int tk = toks[p * 16 + r16];
            if (tk >= 0) {
                float4 v = *reinterpret_cast<const float4*>(&tf[r16 * 516 + c4 * 4]);
                *reinterpret_cast<float4*>(&out[(size_t)tk * O_DIM + c4 * 4]) = v;
            }
        }
    }
}

// ---------------- K5: zero rows of dropped tokens ----------------
__global__ __launch_bounds__(256) void zero_dropped_kernel(const int* __restrict__ dropCount,
        const int* __restrict__ dropList, float* __restrict__ out)
{
    int cnt = *dropCount;
    for (int i = blockIdx.x; i < cnt; i += gridDim.x) {
        int n = dropList[i];
        reinterpret_cast<float2*>(&out[(size_t)n * O_DIM])[threadIdx.x] = make_float2(0.f, 0.f);
    }
}

extern "C" void kernel_launch(void* const* d_in, const int* in_sizes, int n_in,
                              void* d_out, int out_size, void* d_ws, size_t ws_size,
                              hipStream_t stream) {
    (void)in_sizes; (void)n_in; (void)out_size; (void)ws_size;
    const float* x   = (const float*)d_in[0];
    const float* Wg1 = (const float*)d_in[1];
    const float* bg1 = (const float*)d_in[2];
    const float* Wg2 = (const float*)d_in[3];
    const float* bg2 = (const float*)d_in[4];
    const float* W1  = (const float*)d_in[5];
    const float* b1  = (const float*)d_in[6];
    const float* W2  = (const float*)d_in[7];
    const float* b2  = (const float*)d_in[8];
    float* out = (float*)d_out;

    char* ws = (char*)d_ws;
    size_t off = 0;
    int* dropCount   = (int*)(ws + off); off += 256;
    int* top_expert  = (int*)(ws + off); off += (size_t)N_TOK * 4;
    int* blockCounts = (int*)(ws + off); off += 256 * 16 * 4;
    int* blockOffs   = (int*)(ws + off); off += 256 * 16 * 4;
    int* totals      = (int*)(ws + off); off += 256;
    int* slot_token  = (int*)(ws + off); off += (size_t)E_EXP * CAPE * 4;
    int* dropList    = (int*)(ws + off); off += (size_t)N_TOK * 4;
    ushort* W1F      = (ushort*)(ws + off); off += (size_t)E_EXP * D_IN * H_DIM * 2;
    ushort* W2F      = (ushort*)(ws + off); off += (size_t)E_EXP * H_DIM * O_DIM * 2;
    ushort* WgF      = (ushort*)(ws + off); off += (size_t)3 * GHID * D_IN * 2;

    wpack_gate<<<64, 64, 0, stream>>>(Wg1, WgF);
    wpack1_kernel<<<2048, 64, 0, stream>>>(W1, W1F);
    wpack2_kernel<<<2048, 64, 0, stream>>>(W2, W2F);
    gating_mfma_kernel<<<N_TOK / 128, 256, 0, stream>>>(x, WgF, bg1, Wg2, bg2, top_expert);
    count_kernel<<<N_TOK / 512, 256, 0, stream>>>(top_expert, blockCounts);
    scan_kernel<<<1, 64, 0, stream>>>(blockCounts, blockOffs, totals, dropCount);
    scatter_kernel<<<N_TOK / 512, 64, 0, stream>>>(top_expert, blockOffs, slot_token, dropCount, dropList);
    expert_mfma_kernel<<<E_EXP * (CAPE / 64), 512, 0, stream>>>(x, W1F, b1, W2F, b2, slot_token, totals, out);
    zero_dropped_kernel<<<256, 256, 0, stream>>>(dropCount, dropList, out);
}